// Round 1
// baseline (363.774 us; speedup 1.0000x reference)
//
#include <hip/hip_runtime.h>

#define LOG2E_F 1.44269504088896340736f
#define LN2_F   0.69314718055994530942f

static constexpr int NT     = 32;          // num tags
static constexpr int SEQ    = 16384;
static constexpr int LC     = 64;          // steps per phase-1 chunk
static constexpr int CHUNKS = SEQ / LC;    // 256
static constexpr int GROUP  = 8;           // chunks folded per phase-2a block
static constexpr int NB2    = CHUNKS / GROUP; // 32
// START tag = 0, END tag = 1 (masking already applied to `transitions` on host)

__device__ __forceinline__ float redmax32(float v) {
    #pragma unroll
    for (int m = 16; m >= 1; m >>= 1) v = fmaxf(v, __shfl_xor(v, m, 32));
    return v;
}
__device__ __forceinline__ float redsum32(float v) {
    #pragma unroll
    for (int m = 16; m >= 1; m >>= 1) v += __shfl_xor(v, m, 32);
    return v;
}

// ---------------------------------------------------------------------------
// Phase 1: each block computes the exp-domain product of its 64 step-matrices
//   P_c = prod_{t=c*64}^{c*64+63} ( W .* colscale(E_t) ),  W = exp(T)
// with per-row power-of-2 rescaling; emits log2-domain matrix
//   out1[c][i][k] = log2( P_c[i][k] )  (= scale_i + log2(mantissa))
// Exact-zero entries (masked -10000 paths underflow) give -inf: they
// contribute exp(-10000)==0 in the reference's fp32 arithmetic too.
// ---------------------------------------------------------------------------
__global__ __launch_bounds__(1024, 4)
void crf_phase1(const int* __restrict__ x,
                const float* __restrict__ emit,
                const float* __restrict__ trans,
                float* __restrict__ out1)
{
    __shared__ float W[NT * NT];        // exp2 domain transitions
    __shared__ float P[2][NT * NT];     // ping-pong product matrix
    __shared__ float E[LC * NT];        // exp2 domain emissions for this chunk

    const int tid = threadIdx.x;
    const int i   = tid >> 5;           // row
    const int k   = tid & 31;           // col
    const int c   = blockIdx.x;
    const int base = c * LC;

    W[tid] = exp2f(trans[tid] * LOG2E_F);

    #pragma unroll
    for (int r = 0; r < 2; ++r) {
        const int row = (tid >> 5) + 32 * r;      // 0..63
        const int xv  = x[base + row];            // broadcast within 32 lanes
        E[row * NT + k] = exp2f(emit[(size_t)xv * NT + k] * LOG2E_F);
    }
    __syncthreads();

    // W column k into registers (constant across the whole chunk)
    float wcol[NT];
    #pragma unroll
    for (int j = 0; j < NT; ++j) wcol[j] = W[j * NT + k];

    // init P = M_{t0}
    float tmp = W[i * NT + k] * E[k];
    int sInt = 0;
    P[0][tid] = tmp;
    __syncthreads();

    int p = 0;
    for (int t = 1; t < LC; ++t) {
        const float4* prow = (const float4*)&P[p][i * NT];
        float acc = 0.f;
        #pragma unroll
        for (int q = 0; q < 8; ++q) {
            float4 v = prow[q];
            acc += v.x * wcol[4 * q + 0];
            acc += v.y * wcol[4 * q + 1];
            acc += v.z * wcol[4 * q + 2];
            acc += v.w * wcol[4 * q + 3];
        }
        acc *= E[t * NT + k];

        // per-row power-of-2 rescale: rows of a wave are 32-lane groups
        float rm = redmax32(acc);
        int ex = 0;
        if (rm > 0.f) ex = (int)((__float_as_uint(rm) >> 23) & 0xFF) - 127;
        tmp = ldexpf(acc, -ex);   // mantissa-normalized row (max entry in [1,2))
        sInt += ex;               // identical across the row's 32 lanes

        P[p ^ 1][tid] = tmp;
        p ^= 1;
        __syncthreads();          // single barrier/step thanks to ping-pong
    }
    out1[c * (NT * NT) + tid] = (float)sInt + log2f(tmp);  // log2(0) = -inf ok
}

// ---------------------------------------------------------------------------
// Phase 2a: 32 blocks; block b folds chunk matrices [8b .. 8b+7] left-to-right
// with log2-domain matmat combines:  D = D (x) L,
//   D'[i,k] = max_j(D[i,j]+L[j,k]) + log2( sum_j 2^(D[i,j]+L[j,k]-max) )
// ---------------------------------------------------------------------------
__global__ __launch_bounds__(1024, 4)
void crf_phase2a(const float* __restrict__ out1, float* __restrict__ out2)
{
    __shared__ float D[2][NT * NT];
    __shared__ float Lb[NT * NT];

    const int tid = threadIdx.x;
    const int i = tid >> 5, k = tid & 31;
    const int b = blockIdx.x;

    float dcur = out1[(b * GROUP) * (NT * NT) + tid];
    D[0][tid] = dcur;
    int p = 0;
    for (int n = 1; n < GROUP; ++n) {
        Lb[tid] = out1[(b * GROUP + n) * (NT * NT) + tid];
        __syncthreads();                      // Lb + previous D writes visible

        const float4* drow = (const float4*)&D[p][i * NT];
        float vals[NT];
        #pragma unroll
        for (int q = 0; q < 8; ++q) {
            float4 v = drow[q];
            vals[4 * q + 0] = v.x + Lb[(4 * q + 0) * NT + k];
            vals[4 * q + 1] = v.y + Lb[(4 * q + 1) * NT + k];
            vals[4 * q + 2] = v.z + Lb[(4 * q + 2) * NT + k];
            vals[4 * q + 3] = v.w + Lb[(4 * q + 3) * NT + k];
        }
        float m = vals[0];
        #pragma unroll
        for (int j = 1; j < NT; ++j) m = fmaxf(m, vals[j]);
        m = fmaxf(m, -3.0e38f);               // -inf guard: avoids (-inf)-(-inf)
        float s = 0.f;
        #pragma unroll
        for (int j = 0; j < NT; ++j) s += exp2f(vals[j] - m);
        dcur = (s > 0.f) ? (m + log2f(s)) : -__builtin_inff();

        __syncthreads();                      // all reads of D[p]/Lb complete
        D[p ^ 1][tid] = dcur;
        p ^= 1;
    }
    out2[b * (NT * NT) + tid] = dcur;
}

// ---------------------------------------------------------------------------
// Phase 2b: single block. alpha-scan over the 32 folded matrices (log2 domain,
// staged into LDS transposed+padded to kill bank conflicts), then final
// logsumexp with T[:,END], convert to natural log.
// ---------------------------------------------------------------------------
__global__ __launch_bounds__(1024, 2)
void crf_phase2b(const float* __restrict__ out2,
                 const float* __restrict__ trans,
                 float* __restrict__ out)
{
    __shared__ float Lt[GROUP][NT * 33];      // 8 matrices/stage, [k*33 + i]
    __shared__ float la[NT];

    const int tid = threadIdx.x;
    const int k = tid >> 5;                   // output tag (per 32-lane group)
    const int i = tid & 31;                   // summed-over tag (lane in group)

    if (tid < NT) la[tid] = (tid == 0) ? 0.f : -10000.f * LOG2E_F;

    for (int g = 0; g < NB2 / GROUP; ++g) {   // 4 stages of 8 matrices
        __syncthreads();                      // la init / prev-stage reads done
        {
            const int i2 = tid >> 5, k2 = tid & 31;  // matrix row/col of my elem
            #pragma unroll
            for (int n = 0; n < GROUP; ++n) {
                float v = out2[(g * GROUP + n) * (NT * NT) + tid]; // coalesced
                Lt[n][k2 * 33 + i2] = v;      // transposed, padded: conflict-free
            }
        }
        __syncthreads();
        for (int n = 0; n < GROUP; ++n) {
            float val = la[i] + Lt[n][k * 33 + i];
            float m = redmax32(val);
            m = fmaxf(m, -3.0e38f);
            float s = redsum32(exp2f(val - m));
            __syncthreads();                  // all reads of la done
            if (i == 0) la[k] = (s > 0.f) ? (m + log2f(s)) : -__builtin_inff();
            __syncthreads();
        }
    }

    // z = ln2 * log2sumexp_j( la[j] + T[j,END]*log2e )
    if (tid < NT) {
        float v = la[tid] + trans[tid * NT + 1] * LOG2E_F;   // END = 1
        float m = redmax32(v);
        m = fmaxf(m, -3.0e38f);
        float s = redsum32(exp2f(v - m));
        if (tid == 0) out[0] = (m + log2f(s)) * LN2_F;
    }
}

extern "C" void kernel_launch(void* const* d_in, const int* in_sizes, int n_in,
                              void* d_out, int out_size, void* d_ws, size_t ws_size,
                              hipStream_t stream) {
    const int*   x     = (const int*)d_in[0];
    const float* emit  = (const float*)d_in[1];
    const float* trans = (const float*)d_in[2];
    float* out = (float*)d_out;

    float* ws1 = (float*)d_ws;                 // 256 chunk matrices: 1 MB
    float* ws2 = ws1 + CHUNKS * NT * NT;       // 32 folded matrices: 128 KB

    crf_phase1 <<<CHUNKS, 1024, 0, stream>>>(x, emit, trans, ws1);
    crf_phase2a<<<NB2,    1024, 0, stream>>>(ws1, ws2);
    crf_phase2b<<<1,      1024, 0, stream>>>(ws2, trans, out);
}

// Round 2
// 328.146 us; speedup vs baseline: 1.1086x; 1.1086x over previous
//
#include <hip/hip_runtime.h>

#define LOG2E 1.44269504088896340736f
#define LN2   0.69314718055994530942f

static constexpr int NT     = 32;          // num tags
static constexpr int SEQ    = 16384;
static constexpr int LC     = 64;          // steps per phase-1 chunk (1 wave/chunk)
static constexpr int CHUNKS = SEQ / LC;    // 256
static constexpr int GROUP  = 16;          // chunks folded per phase-2a wave
static constexpr int NB2    = CHUNKS / GROUP; // 16
// START = 0, END = 1 (masking already applied to `transitions` on host)

typedef __attribute__((ext_vector_type(8)))  short short8;     // 8 bf16 (4 VGPRs)
typedef __attribute__((ext_vector_type(16))) float float16_t;  // MFMA 32x32 acc

union U8 { unsigned u[4]; short8 s; };

// round-half-up fp32 -> bf16, pack two into one u32 (lo = a, hi = b)
__device__ __forceinline__ unsigned pack_bf16(float a, float b) {
    unsigned ua = (__float_as_uint(a) + 0x8000u) >> 16;
    unsigned ub = (__float_as_uint(b) + 0x8000u) & 0xFFFF0000u;
    return ua | ub;
}

__device__ __forceinline__ float wave_max(float v) {
    #pragma unroll
    for (int m = 1; m <= 32; m <<= 1) v = fmaxf(v, __shfl_xor(v, m, 64));
    return v;
}

// Transpose fix: C-layout (lane holds col c, rows 4h+(reg&3)+8(reg>>2)) ->
// B-fragment (lane holds col c, k = 8h+j contiguous). Pure half-lane exchange.
#define PACK_SWAP_TO_B(ACC, B0, B1)                                          \
    {                                                                        \
        unsigned P0 = pack_bf16(ACC[0],  ACC[1]);                            \
        unsigned P1 = pack_bf16(ACC[2],  ACC[3]);                            \
        unsigned P2 = pack_bf16(ACC[4],  ACC[5]);                            \
        unsigned P3 = pack_bf16(ACC[6],  ACC[7]);                            \
        unsigned P4 = pack_bf16(ACC[8],  ACC[9]);                            \
        unsigned P5 = pack_bf16(ACC[10], ACC[11]);                           \
        unsigned P6 = pack_bf16(ACC[12], ACC[13]);                           \
        unsigned P7 = pack_bf16(ACC[14], ACC[15]);                           \
        unsigned q0 = __shfl_xor(P0, 32, 64), q1 = __shfl_xor(P1, 32, 64);   \
        unsigned q2 = __shfl_xor(P2, 32, 64), q3 = __shfl_xor(P3, 32, 64);   \
        unsigned q4 = __shfl_xor(P4, 32, 64), q5 = __shfl_xor(P5, 32, 64);   \
        unsigned q6 = __shfl_xor(P6, 32, 64), q7 = __shfl_xor(P7, 32, 64);   \
        B0.u[0] = hi ? q2 : P0; B0.u[1] = hi ? q3 : P1;                      \
        B0.u[2] = hi ? P2 : q0; B0.u[3] = hi ? P3 : q1;                      \
        B1.u[0] = hi ? q6 : P4; B1.u[1] = hi ? q7 : P5;                      \
        B1.u[2] = hi ? P6 : q4; B1.u[3] = hi ? P7 : q5;                      \
    }

#define IDENTITY_B(B0, B1)                                                   \
    {                                                                        \
        _Pragma("unroll")                                                    \
        for (int q = 0; q < 4; ++q) {                                        \
            unsigned lo = ((8*h + 2*q)     == c) ? 0x3F80u : 0u;             \
            unsigned hb = ((8*h + 2*q + 1) == c) ? 0x3F80u : 0u;             \
            B0.u[q] = lo | (hb << 16);                                       \
            lo = ((16 + 8*h + 2*q)     == c) ? 0x3F80u : 0u;                 \
            hb = ((16 + 8*h + 2*q + 1) == c) ? 0x3F80u : 0u;                 \
            B1.u[q] = lo | (hb << 16);                                       \
        }                                                                    \
    }

// ---------------------------------------------------------------------------
// Phase 1: one wave per 64-step chunk. Maintains Q = P^T in bf16 MFMA frags:
//   Q <- diag(E_t) * W^T * Q      (A = W^T constant, B = Q, 2 MFMAs/step)
// Power-of-2 matrix rescale every 4 steps (tracked in sInt). Emits
// out1[c][r*32+cc] = log2(Q[r][cc]) - log2(Qmax)   (<= 0, -inf for zeros)
// out1S[c] = log2(Qmax)  (side scalar).
// ---------------------------------------------------------------------------
__global__ __launch_bounds__(64, 1)
void crf_phase1(const int* __restrict__ x, const float* __restrict__ emit,
                const float* __restrict__ trans,
                float* __restrict__ out1, float* __restrict__ out1S)
{
    __shared__ __align__(16) float E[LC * NT];
    const int L = threadIdx.x;
    const int c = L & 31;              // A row m / B,D col
    const int h = L >> 5;
    const bool hi = (h != 0);
    const int chunk = blockIdx.x;

    // ---- stage exp2(emit * log2e) for this chunk into LDS ----
    int xv = x[chunk * LC + L];
    float ev[32];
    #pragma unroll
    for (int rr = 0; rr < 32; ++rr) {
        int t = 2 * rr + h;
        int xt = __shfl(xv, t, 64);
        ev[rr] = emit[(size_t)xt * NT + c];
    }
    #pragma unroll
    for (int rr = 0; rr < 32; ++rr) {
        int t = 2 * rr + h;
        E[t * NT + c] = exp2f(ev[rr] * LOG2E);
    }
    __syncthreads();

    // ---- constant A-fragment: W^T, i.e. A[m=c][k] = exp2(trans[k*32+c]) ----
    U8 A0, A1;
    #pragma unroll
    for (int q = 0; q < 4; ++q) {
        float w0 = exp2f(trans[(8*h + 2*q    ) * NT + c] * LOG2E);
        float w1 = exp2f(trans[(8*h + 2*q + 1) * NT + c] * LOG2E);
        A0.u[q] = pack_bf16(w0, w1);
        float w2 = exp2f(trans[(16 + 8*h + 2*q    ) * NT + c] * LOG2E);
        float w3 = exp2f(trans[(16 + 8*h + 2*q + 1) * NT + c] * LOG2E);
        A1.u[q] = pack_bf16(w2, w3);
    }

    U8 B0, B1;
    IDENTITY_B(B0, B1);

    int sInt = 0;
    float16_t acc;
    for (int t = 0; t < LC; ++t) {
        float16_t z = {};
        acc = __builtin_amdgcn_mfma_f32_32x32x16_bf16(A0.s, B0.s, z,   0, 0, 0);
        acc = __builtin_amdgcn_mfma_f32_32x32x16_bf16(A1.s, B1.s, acc, 0, 0, 0);

        // row scale by E_t: row r = 4h + (reg&3) + 8*(reg>>2)
        const float* Et = &E[t * NT + 4 * h];
        float4 e0 = *(const float4*)(Et);
        float4 e1 = *(const float4*)(Et + 8);
        float4 e2 = *(const float4*)(Et + 16);
        float4 e3 = *(const float4*)(Et + 24);
        acc[0]  *= e0.x; acc[1]  *= e0.y; acc[2]  *= e0.z; acc[3]  *= e0.w;
        acc[4]  *= e1.x; acc[5]  *= e1.y; acc[6]  *= e1.z; acc[7]  *= e1.w;
        acc[8]  *= e2.x; acc[9]  *= e2.y; acc[10] *= e2.z; acc[11] *= e2.w;
        acc[12] *= e3.x; acc[13] *= e3.y; acc[14] *= e3.z; acc[15] *= e3.w;

        if ((t & 3) == 3) {            // power-of-2 matrix rescale
            float mx = acc[0];
            #pragma unroll
            for (int i = 1; i < 16; ++i) mx = fmaxf(mx, acc[i]);
            mx = wave_max(mx);
            if (mx >= 1.1754944e-38f) {
                int ex = (int)((__float_as_uint(mx) >> 23) & 255) - 127;
                #pragma unroll
                for (int i = 0; i < 16; ++i) acc[i] = ldexpf(acc[i], -ex);
                sInt += ex;
            }
        }
        PACK_SWAP_TO_B(acc, B0, B1);
    }

    // ---- normalized log2 output ----
    float mx = acc[0];
    #pragma unroll
    for (int i = 1; i < 16; ++i) mx = fmaxf(mx, acc[i]);
    mx = wave_max(mx);
    float lm = log2f(mx);
    float* o = out1 + (size_t)chunk * (NT * NT);
    #pragma unroll
    for (int i = 0; i < 16; ++i) {
        int r = 4 * h + (i & 3) + 8 * (i >> 2);
        o[r * NT + c] = log2f(acc[i]) - lm;   // <= 0; log2(0) = -inf ok
    }
    if (L == 0) out1S[chunk] = (float)sInt + lm;
}

// ---------------------------------------------------------------------------
// Phase 2a: one wave per 16-chunk group. X <- Q_n * X via MFMA (A = exp2 of
// stored logs, values in [0,1]); rescale every fold; out2 = log2(X) + scalars.
// ---------------------------------------------------------------------------
__global__ __launch_bounds__(64, 1)
void crf_phase2a(const float* __restrict__ out1, const float* __restrict__ out1S,
                 float* __restrict__ out2)
{
    const int L = threadIdx.x;
    const int c = L & 31;
    const int h = L >> 5;
    const bool hi = (h != 0);
    const int w = blockIdx.x;

    U8 B0, B1;
    IDENTITY_B(B0, B1);

    float SC = 0.f;
    #pragma unroll
    for (int n = 0; n < GROUP; ++n) SC += out1S[w * GROUP + n];

    const float* src = out1 + (size_t)(w * GROUP) * (NT * NT) + c * NT + 8 * h;
    float4 a0 = *(const float4*)(src);
    float4 a1 = *(const float4*)(src + 4);
    float4 a2 = *(const float4*)(src + 16);
    float4 a3 = *(const float4*)(src + 20);

    int sInt = 0;
    float16_t acc;
    for (int n = 0; n < GROUP; ++n) {
        U8 A0, A1;
        A0.u[0] = pack_bf16(exp2f(a0.x), exp2f(a0.y));
        A0.u[1] = pack_bf16(exp2f(a0.z), exp2f(a0.w));
        A0.u[2] = pack_bf16(exp2f(a1.x), exp2f(a1.y));
        A0.u[3] = pack_bf16(exp2f(a1.z), exp2f(a1.w));
        A1.u[0] = pack_bf16(exp2f(a2.x), exp2f(a2.y));
        A1.u[1] = pack_bf16(exp2f(a2.z), exp2f(a2.w));
        A1.u[2] = pack_bf16(exp2f(a3.x), exp2f(a3.y));
        A1.u[3] = pack_bf16(exp2f(a3.z), exp2f(a3.w));

        if (n + 1 < GROUP) {           // depth-1 prefetch
            const float* s2 = out1 + (size_t)(w * GROUP + n + 1) * (NT * NT)
                              + c * NT + 8 * h;
            a0 = *(const float4*)(s2);
            a1 = *(const float4*)(s2 + 4);
            a2 = *(const float4*)(s2 + 16);
            a3 = *(const float4*)(s2 + 20);
        }

        float16_t z = {};
        acc = __builtin_amdgcn_mfma_f32_32x32x16_bf16(A0.s, B0.s, z,   0, 0, 0);
        acc = __builtin_amdgcn_mfma_f32_32x32x16_bf16(A1.s, B1.s, acc, 0, 0, 0);

        float mx = acc[0];
        #pragma unroll
        for (int i = 1; i < 16; ++i) mx = fmaxf(mx, acc[i]);
        mx = wave_max(mx);
        if (mx >= 1.1754944e-38f) {
            int ex = (int)((__float_as_uint(mx) >> 23) & 255) - 127;
            #pragma unroll
            for (int i = 0; i < 16; ++i) acc[i] = ldexpf(acc[i], -ex);
            sInt += ex;
        }
        PACK_SWAP_TO_B(acc, B0, B1);
    }

    float* o = out2 + (size_t)w * (NT * NT);
    float addc = (float)sInt + SC;
    #pragma unroll
    for (int i = 0; i < 16; ++i) {
        int r = 4 * h + (i & 3) + 8 * (i >> 2);
        o[r * NT + c] = log2f(acc[i]) + addc;
    }
}

// ---------------------------------------------------------------------------
// Phase 2b: single wave. alpha <- logsumexp(X_n[r][:] + alpha) over 16 folded
// matrices (log2 domain), then final lse with T[:,END], convert to ln.
// ---------------------------------------------------------------------------
__global__ __launch_bounds__(64, 1)
void crf_phase2b(const float* __restrict__ out2, const float* __restrict__ trans,
                 float* __restrict__ out)
{
    __shared__ __align__(16) float al[NT];
    const int L = threadIdx.x;
    const int r = L & 31;
    const int h = L >> 5;

    if (L < NT) al[L] = (L == 0) ? 0.f : -10000.f * LOG2E;
    __syncthreads();

    const float* src = out2 + r * NT + 16 * h;
    float4 v0 = *(const float4*)(src);
    float4 v1 = *(const float4*)(src + 4);
    float4 v2 = *(const float4*)(src + 8);
    float4 v3 = *(const float4*)(src + 12);

    for (int n = 0; n < NB2; ++n) {
        float vals[16] = {v0.x, v0.y, v0.z, v0.w, v1.x, v1.y, v1.z, v1.w,
                          v2.x, v2.y, v2.z, v2.w, v3.x, v3.y, v3.z, v3.w};
        if (n + 1 < NB2) {             // depth-1 prefetch
            const float* s2 = out2 + (size_t)(n + 1) * (NT * NT) + r * NT + 16 * h;
            v0 = *(const float4*)(s2);
            v1 = *(const float4*)(s2 + 4);
            v2 = *(const float4*)(s2 + 8);
            v3 = *(const float4*)(s2 + 12);
        }
        const float4* ap = (const float4*)&al[16 * h];
        float4 A0 = ap[0], A1 = ap[1], A2 = ap[2], A3 = ap[3];
        float aj[16] = {A0.x, A0.y, A0.z, A0.w, A1.x, A1.y, A1.z, A1.w,
                        A2.x, A2.y, A2.z, A2.w, A3.x, A3.y, A3.z, A3.w};
        float mv = -3.0e38f;
        #pragma unroll
        for (int j = 0; j < 16; ++j) {
            vals[j] = fmaxf(vals[j], -1e30f) + fmaxf(aj[j], -1e30f);
            mv = fmaxf(mv, vals[j]);
        }
        mv = fmaxf(mv, __shfl_xor(mv, 32, 64));
        float s = 0.f;
        #pragma unroll
        for (int j = 0; j < 16; ++j) s += exp2f(vals[j] - mv);
        s += __shfl_xor(s, 32, 64);
        float nal = mv + log2f(s);
        __syncthreads();
        if (h == 0) al[r] = nal;
        __syncthreads();
    }

    // z = ln2 * lse2_j( al[j] + T[j,END]*log2e ),  END = 1
    float v = fmaxf(al[r], -1e30f) + trans[r * NT + 1] * LOG2E;
    float mv = v;
    #pragma unroll
    for (int m = 1; m <= 16; m <<= 1) mv = fmaxf(mv, __shfl_xor(mv, m, 64));
    float s = exp2f(v - mv);
    #pragma unroll
    for (int m = 1; m <= 16; m <<= 1) s += __shfl_xor(s, m, 64);
    if (L == 0) out[0] = (mv + log2f(s)) * LN2;
}

extern "C" void kernel_launch(void* const* d_in, const int* in_sizes, int n_in,
                              void* d_out, int out_size, void* d_ws, size_t ws_size,
                              hipStream_t stream) {
    const int*   x     = (const int*)d_in[0];
    const float* emit  = (const float*)d_in[1];
    const float* trans = (const float*)d_in[2];
    float* out = (float*)d_out;

    float* ws1   = (float*)d_ws;                    // 256 chunk mats (1 MB)
    float* ws2   = ws1 + (size_t)CHUNKS * NT * NT;  // 16 folded mats
    float* ws1S  = ws2 + (size_t)NB2 * NT * NT;     // 256 side scalars

    crf_phase1 <<<CHUNKS, 64, 0, stream>>>(x, emit, trans, ws1, ws1S);
    crf_phase2a<<<NB2,    64, 0, stream>>>(ws1, ws1S, ws2);
    crf_phase2b<<<1,      64, 0, stream>>>(ws2, trans, out);
}